// Round 1
// baseline (44.559 us; speedup 1.0000x reference)
//
#include <hip/hip_runtime.h>
#include <math.h>

// Problem constants: B=16, N=1024, D=3
#define BN     16384          // B*N points
#define NPTS   1024           // points per batch
#define EPSF   1e-8f

// ws layout (in floats):
//   [0, 64)          partialDiff  (one per kA block)
//   [64, 128)        partialEmd
//   [128, 640)       partialCh    (one per kB block; even bid = dl, odd = dr)
//   [1024, 66560)    xn  as float4[16384]  (clipped+normalized pred)
//   [66560, 132096)  yn  as float4[16384]  (clipped+normalized target)
#define OFF_PD 0
#define OFF_PE 64
#define OFF_PC 128
#define OFF_XN 1024
#define OFF_YN (1024 + 4*BN)

__device__ __forceinline__ float clampf(float v, float lo, float hi) {
    return fminf(fmaxf(v, lo), hi);
}

// Kernel A: per-point work — diffusion MSE partial, EMD matched distance,
// and store clipped-normalized points for the chamfer kernel.
__global__ __launch_bounds__(256) void kA(
    const float* __restrict__ npred, const float* __restrict__ ntgt,
    const float* __restrict__ pp,    const float* __restrict__ tp,
    const int*   __restrict__ assign, float* __restrict__ ws) {
    const int tid = threadIdx.x;
    const int p   = blockIdx.x * 256 + tid;   // 0..16383
    const int base = 3 * p;

    // diffusion: (noise_pred - noise_target)^2 over this point's 3 comps
    float a0 = npred[base], a1 = npred[base + 1], a2 = npred[base + 2];
    float b0 = ntgt[base],  b1 = ntgt[base + 1],  b2 = ntgt[base + 2];
    float d0 = a0 - b0, d1 = a1 - b1, d2 = a2 - b2;
    float diff = d0 * d0 + d1 * d1 + d2 * d2;

    float px = pp[base], py = pp[base + 1], pz = pp[base + 2];
    float tx = tp[base], ty = tp[base + 1], tz = tp[base + 2];

    // EMD: gather matched target, clip to [-2,2], L2 distance, floor at EPS
    int b = p >> 10;                 // batch
    int a = assign[p];               // matched column in this batch
    int qb = 3 * ((b << 10) + a);
    float mx = tp[qb], my = tp[qb + 1], mz = tp[qb + 2];
    float ex = clampf(px, -2.f, 2.f) - clampf(mx, -2.f, 2.f);
    float ey = clampf(py, -2.f, 2.f) - clampf(my, -2.f, 2.f);
    float ez = clampf(pz, -2.f, 2.f) - clampf(mz, -2.f, 2.f);
    float ed = fmaxf(sqrtf(ex * ex + ey * ey + ez * ez), EPSF);

    // chamfer prep: clip to [-1,1], normalize with EPS floor, store padded
    float cx = clampf(px, -1.f, 1.f), cy = clampf(py, -1.f, 1.f), cz = clampf(pz, -1.f, 1.f);
    float cn = fmaxf(sqrtf(cx * cx + cy * cy + cz * cz), EPSF);
    float rcn = 1.0f / cn;
    ((float4*)(ws + OFF_XN))[p] = make_float4(cx * rcn, cy * rcn, cz * rcn, 0.f);

    float gx = clampf(tx, -1.f, 1.f), gy = clampf(ty, -1.f, 1.f), gz = clampf(tz, -1.f, 1.f);
    float gn = fmaxf(sqrtf(gx * gx + gy * gy + gz * gz), EPSF);
    float rgn = 1.0f / gn;
    ((float4*)(ws + OFF_YN))[p] = make_float4(gx * rgn, gy * rgn, gz * rgn, 0.f);

    // deterministic block reduction (wave shfl + LDS across 4 waves)
    for (int o = 32; o; o >>= 1) {
        diff += __shfl_down(diff, o, 64);
        ed   += __shfl_down(ed,   o, 64);
    }
    __shared__ float sd[4], se[4];
    int w = tid >> 6;
    if ((tid & 63) == 0) { sd[w] = diff; se[w] = ed; }
    __syncthreads();
    if (tid == 0) {
        ws[OFF_PD + blockIdx.x] = sd[0] + sd[1] + sd[2] + sd[3];
        ws[OFF_PE + blockIdx.x] = se[0] + se[1] + se[2] + se[3];
    }
}

// Kernel B: chamfer min-distance, both directions.
// grid = 2 * 16 * 16 = 512 blocks. bid&1 = direction; each block handles
// 64 rows of the "first" cloud, staging the full "second" cloud in LDS.
// 4 threads per row, each scans a 256-wide j strip (skewed for bank-conflict-
// free float4 LDS reads), then shfl-min across the 4.
__global__ __launch_bounds__(256) void kB(float* __restrict__ ws) {
    const int bid  = blockIdx.x;
    const int dir  = bid & 1;         // 0: dl (x rows vs y), 1: dr (y rows vs x)
    const int rest = bid >> 1;        // 0..255
    const int b    = rest >> 4;       // batch 0..15
    const int c    = rest & 15;       // row chunk 0..15

    const float4* xn4 = (const float4*)(ws + OFF_XN);
    const float4* yn4 = (const float4*)(ws + OFF_YN);
    const float4* first  = dir ? yn4 : xn4;
    const float4* second = dir ? xn4 : yn4;

    __shared__ float4 sec[NPTS];      // 16 KB
    const int tid = threadIdx.x;
    for (int t = tid; t < NPTS; t += 256) sec[t] = second[(b << 10) + t];
    __syncthreads();

    const int s = tid & 3;            // j-strip index
    const int r = tid >> 2;           // row within chunk (0..63)
    const int i = c * 64 + r;
    float4 f = first[(b << 10) + i];

    float minss = 3.0e38f;
    const int jbase = s << 8;
    const int skew  = s << 1;         // 2*s: banks (4k+8s)%32 disjoint across s
    #pragma unroll 8
    for (int k = 0; k < 256; ++k) {
        int j = jbase + ((k + skew) & 255);
        float4 g = sec[j];
        float dx = f.x - g.x, dy = f.y - g.y, dz = f.z - g.z;
        float ss = dx * dx + dy * dy + dz * dz;
        minss = fminf(minss, ss);
    }
    // min across the 4 strip-threads (adjacent lanes)
    minss = fminf(minss, __shfl_xor(minss, 1, 64));
    minss = fminf(minss, __shfl_xor(minss, 2, 64));

    float val = 0.f;
    if (s == 0) {
        float dist = fmaxf(sqrtf(fmaxf(minss, 0.f)), EPSF);
        float ld = clampf(logf(dist + EPSF), -10.f, 10.f);
        val = expf(ld);
    }
    // deterministic block sum of the 64 row values
    for (int o = 32; o; o >>= 1) val += __shfl_down(val, o, 64);
    __shared__ float sv[4];
    int w = tid >> 6;
    if ((tid & 63) == 0) sv[w] = val;
    __syncthreads();
    if (tid == 0) ws[OFF_PC + bid] = sv[0] + sv[1] + sv[2] + sv[3];
}

// Kernel C: final deterministic combine.
__global__ __launch_bounds__(256) void kC(const float* __restrict__ ws,
                                          float* __restrict__ out) {
    const int tid = threadIdx.x;
    float sdiff = 0.f, semd = 0.f;
    if (tid < 64) { sdiff = ws[OFF_PD + tid]; semd = ws[OFF_PE + tid]; }
    float sdl = ws[OFF_PC + 2 * tid];       // even bids: dl
    float sdr = ws[OFF_PC + 2 * tid + 1];   // odd bids: dr

    for (int o = 32; o; o >>= 1) {
        sdiff += __shfl_down(sdiff, o, 64);
        semd  += __shfl_down(semd,  o, 64);
        sdl   += __shfl_down(sdl,   o, 64);
        sdr   += __shfl_down(sdr,   o, 64);
    }
    __shared__ float r[4][4];
    int w = tid >> 6;
    if ((tid & 63) == 0) { r[w][0] = sdiff; r[w][1] = semd; r[w][2] = sdl; r[w][3] = sdr; }
    __syncthreads();
    if (tid == 0) {
        float Sd = r[0][0] + r[1][0] + r[2][0] + r[3][0];
        float Se = r[0][1] + r[1][1] + r[2][1] + r[3][1];
        float Sl = r[0][2] + r[1][2] + r[2][2] + r[3][2];
        float Sr = r[0][3] + r[1][3] + r[2][3] + r[3][3];
        float diffusion = Sd * (1.0f / 49152.0f);          // /(B*N*D)
        float cd        = 0.5f * (Sl + Sr) * (1.0f / 16384.0f);
        float emd       = Se * (1.0f / 16384.0f);
        out[0] = 1.0f * diffusion + 0.1f * cd + 0.05f * emd;
    }
}

extern "C" void kernel_launch(void* const* d_in, const int* in_sizes, int n_in,
                              void* d_out, int out_size, void* d_ws, size_t ws_size,
                              hipStream_t stream) {
    const float* npred  = (const float*)d_in[0];
    const float* ntgt   = (const float*)d_in[1];
    const float* pp     = (const float*)d_in[2];
    const float* tp     = (const float*)d_in[3];
    const int*   assign = (const int*)d_in[4];
    float* ws  = (float*)d_ws;
    float* out = (float*)d_out;

    hipLaunchKernelGGL(kA, dim3(64),  dim3(256), 0, stream, npred, ntgt, pp, tp, assign, ws);
    hipLaunchKernelGGL(kB, dim3(512), dim3(256), 0, stream, ws);
    hipLaunchKernelGGL(kC, dim3(1),   dim3(256), 0, stream, ws, out);
}

// Round 2
// 26.970 us; speedup vs baseline: 1.6521x; 1.6521x over previous
//
#include <hip/hip_runtime.h>
#include <math.h>

// Problem constants: B=16, N=1024, D=3
#define BN      16384         // B*N points
#define NPTS    1024          // points per batch
#define EPSF    1e-8f
#define STRIDE4 257           // padded float4 strip stride: banks 4(s+k)+{0,4,8,12}

// ws layout (floats):
//   [0, 512)    chamfer partial per block (even bid = dl, odd bid = dr)
//   [512, 1024) side partial per block (even bid = diffusion, odd bid = emd)
#define OFF_PC 0
#define OFF_PS 512

__device__ __forceinline__ float clampf(float v, float lo, float hi) {
    return fminf(fmaxf(v, lo), hi);
}

// One kernel does everything except the final combine.
// grid = 512: bid&1 = chamfer direction; (bid>>1) = batch*16 + rowchunk.
// Each block: stages+normalizes the full "second" cloud of its batch into LDS
// (padded strips -> conflict-free broadcast reads), handles 64 rows of the
// "first" cloud with 4 j-strip threads per row, and folds a slice of the
// diffusion MSE (dir0) or EMD gather distance (dir1) in as side work.
__global__ __launch_bounds__(256) void kMain(
    const float* __restrict__ npred, const float* __restrict__ ntgt,
    const float* __restrict__ pp,    const float* __restrict__ tp,
    const int*   __restrict__ assign, float* __restrict__ ws) {
    const int bid  = blockIdx.x;
    const int dir  = bid & 1;         // 0: dl (pred rows vs target), 1: dr
    const int rest = bid >> 1;        // 0..255
    const int b    = rest >> 4;       // batch
    const int c    = rest & 15;       // 64-row chunk
    const int tid  = threadIdx.x;

    __shared__ float4 sec[4 * STRIDE4];   // 16448 B

    const float* secSrc = dir ? pp : tp;
    const float* firSrc = dir ? tp : pp;

    // Stage + clip + normalize the second cloud. Thread t handles points
    // q = t + 256*m; writes strip m slot t (coalesced 12B global reads).
    const float* sbase = secSrc + b * 3072;
    #pragma unroll
    for (int m = 0; m < 4; ++m) {
        int q = (m << 8) + tid;
        float x = sbase[3 * q], y = sbase[3 * q + 1], z = sbase[3 * q + 2];
        x = clampf(x, -1.f, 1.f); y = clampf(y, -1.f, 1.f); z = clampf(z, -1.f, 1.f);
        float n = fmaxf(sqrtf(x * x + y * y + z * z), EPSF);
        float r = 1.0f / n;
        sec[m * STRIDE4 + tid] = make_float4(x * r, y * r, z * r, 0.f);
    }

    // Side work (overlaps staging latency).
    float side = 0.f;
    if (dir == 0) {
        // diffusion: 12288 float4 over 256 dir0-blocks -> 48 float4/block
        if (tid < 48) {
            int idx = rest * 48 + tid;
            float4 a  = ((const float4*)npred)[idx];
            float4 bb = ((const float4*)ntgt)[idx];
            float d0 = a.x - bb.x, d1 = a.y - bb.y, d2 = a.z - bb.z, d3 = a.w - bb.w;
            side = d0 * d0 + d1 * d1 + d2 * d2 + d3 * d3;
        }
    } else {
        // EMD: 16384 points over 256 dir1-blocks -> 64 points/block
        if (tid < 64) {
            int p    = rest * 64 + tid;
            int base = 3 * p;
            float px = pp[base], py = pp[base + 1], pz = pp[base + 2];
            int bb = p >> 10;
            int a  = assign[p];
            int qb = 3 * ((bb << 10) + a);
            float mx = tp[qb], my = tp[qb + 1], mz = tp[qb + 2];
            float ex = clampf(px, -2.f, 2.f) - clampf(mx, -2.f, 2.f);
            float ey = clampf(py, -2.f, 2.f) - clampf(my, -2.f, 2.f);
            float ez = clampf(pz, -2.f, 2.f) - clampf(mz, -2.f, 2.f);
            side = fmaxf(sqrtf(ex * ex + ey * ey + ez * ez), EPSF);
        }
    }

    __syncthreads();

    // My row of the first cloud (4 strip-lanes recompute the same row — cheap).
    const int s = tid & 3;
    const int r = tid >> 2;
    const int i = c * 64 + r;
    const float* fb = firSrc + b * 3072 + 3 * i;
    float fx = clampf(fb[0], -1.f, 1.f);
    float fy = clampf(fb[1], -1.f, 1.f);
    float fz = clampf(fb[2], -1.f, 1.f);
    float fn = fmaxf(sqrtf(fx * fx + fy * fy + fz * fz), EPSF);
    float rf = 1.0f / fn;
    fx *= rf; fy *= rf; fz *= rf;

    // min ||a-b||^2 = 2 - 2*max(a.b) on unit vectors.
    const float4* srow = sec + s * STRIDE4;
    float dmax = -4.f;
    #pragma unroll 8
    for (int k = 0; k < 256; ++k) {
        float4 g = srow[k];
        float dot = fmaf(fx, g.x, fmaf(fy, g.y, fz * g.z));
        dmax = fmaxf(dmax, dot);
    }
    dmax = fmaxf(dmax, __shfl_xor(dmax, 1, 64));
    dmax = fmaxf(dmax, __shfl_xor(dmax, 2, 64));

    float val = 0.f;
    if (s == 0) {
        float ss   = fmaxf(2.f - 2.f * dmax, 0.f);
        float dist = fmaxf(sqrtf(ss), EPSF);
        float ld   = clampf(logf(dist + EPSF), -10.f, 10.f);
        val = expf(ld);
    }

    // Deterministic block reduction of (val, side).
    for (int o = 32; o; o >>= 1) {
        val  += __shfl_down(val,  o, 64);
        side += __shfl_down(side, o, 64);
    }
    __shared__ float sv[4], sw[4];
    int w = tid >> 6;
    if ((tid & 63) == 0) { sv[w] = val; sw[w] = side; }
    __syncthreads();
    if (tid == 0) {
        ws[OFF_PC + bid] = sv[0] + sv[1] + sv[2] + sv[3];
        ws[OFF_PS + bid] = sw[0] + sw[1] + sw[2] + sw[3];
    }
}

// Final deterministic combine: 512 chamfer partials + 512 side partials.
__global__ __launch_bounds__(256) void kC(const float* __restrict__ ws,
                                          float* __restrict__ out) {
    const int tid = threadIdx.x;
    float dl = ws[OFF_PC + 2 * tid];       // even bid: dl
    float dr = ws[OFF_PC + 2 * tid + 1];   // odd bid: dr
    float sd = ws[OFF_PS + 2 * tid];       // even bid: diffusion
    float se = ws[OFF_PS + 2 * tid + 1];   // odd bid: emd

    for (int o = 32; o; o >>= 1) {
        dl += __shfl_down(dl, o, 64);
        dr += __shfl_down(dr, o, 64);
        sd += __shfl_down(sd, o, 64);
        se += __shfl_down(se, o, 64);
    }
    __shared__ float rr[4][4];
    int w = tid >> 6;
    if ((tid & 63) == 0) { rr[w][0] = dl; rr[w][1] = dr; rr[w][2] = sd; rr[w][3] = se; }
    __syncthreads();
    if (tid == 0) {
        float Sl = rr[0][0] + rr[1][0] + rr[2][0] + rr[3][0];
        float Sr = rr[0][1] + rr[1][1] + rr[2][1] + rr[3][1];
        float Sd = rr[0][2] + rr[1][2] + rr[2][2] + rr[3][2];
        float Se = rr[0][3] + rr[1][3] + rr[2][3] + rr[3][3];
        float diffusion = Sd * (1.0f / 49152.0f);
        float cd        = 0.5f * (Sl + Sr) * (1.0f / 16384.0f);
        float emd       = Se * (1.0f / 16384.0f);
        out[0] = diffusion + 0.1f * cd + 0.05f * emd;
    }
}

extern "C" void kernel_launch(void* const* d_in, const int* in_sizes, int n_in,
                              void* d_out, int out_size, void* d_ws, size_t ws_size,
                              hipStream_t stream) {
    const float* npred  = (const float*)d_in[0];
    const float* ntgt   = (const float*)d_in[1];
    const float* pp     = (const float*)d_in[2];
    const float* tp     = (const float*)d_in[3];
    const int*   assign = (const int*)d_in[4];
    float* ws  = (float*)d_ws;
    float* out = (float*)d_out;

    hipLaunchKernelGGL(kMain, dim3(512), dim3(256), 0, stream, npred, ntgt, pp, tp, assign, ws);
    hipLaunchKernelGGL(kC,    dim3(1),   dim3(256), 0, stream, ws, out);
}